// Round 11
// baseline (254.945 us; speedup 1.0000x reference)
//
#include <hip/hip_runtime.h>
#include <hip/hip_bf16.h>

typedef __hip_bfloat16 bf16;
using f32x4v = __attribute__((ext_vector_type(4))) float;
using bf16x8 = __attribute__((ext_vector_type(8))) short;

#define N_NODES 25000
#define N_PAD   25024   // multiple of 32 for conv kernel tiles
#define N_EDGES 400000
#define N_GR    100
#define SCAN_C  25      // 1024 * 25 = 25600 >= N_NODES

__device__ __forceinline__ bf16 tob(float v) { return __float2bfloat16(v); }
__device__ __forceinline__ unsigned short tobu(float v) {
  union { bf16 b; unsigned short u; } c; c.b = __float2bfloat16(v); return c.u;
}
__device__ __forceinline__ float b2f(unsigned short u) { return __uint_as_float(((unsigned)u) << 16); }
// clamp-free tanh: 1 - 2/(e^{2x}+1); inf-safe
__device__ __forceinline__ float tanh_fast(float x) {
  float e = __expf(2.f * x);
  return 1.f - 2.f * __builtin_amdgcn_rcpf(e + 1.f);
}

// ---------------- CSR build ----------------
__global__ __launch_bounds__(256) void hist_kernel(const int* __restrict__ dst, int* __restrict__ deg, int E) {
  int e = blockIdx.x * blockDim.x + threadIdx.x;
  if (e < E) atomicAdd(&deg[dst[e]], 1);
}

// one-pass scan: thread-local 25-chunk scan in registers + block scan of totals
__global__ __launch_bounds__(1024) void scan_kernel(const int* __restrict__ deg, int* __restrict__ offs,
                                                    int* __restrict__ cur, int n) {
  __shared__ int wsum[16];
  __shared__ int wpre[16];
  int t = threadIdx.x, lane = t & 63, w = t >> 6;
  int base = t * SCAN_C;
  int loc[SCAN_C];
  int s = 0;
  #pragma unroll
  for (int i = 0; i < SCAN_C; i++) {
    int idx = base + i;
    int v = (idx < n) ? deg[idx] : 0;
    loc[i] = s; s += v;
  }
  int x = s;
  #pragma unroll
  for (int sh = 1; sh < 64; sh <<= 1) { int y = __shfl_up(x, sh); if (lane >= sh) x += y; }
  if (lane == 63) wsum[w] = x;
  __syncthreads();
  if (w == 0 && lane < 16) {
    int ws_ = wsum[lane], xs = ws_;
    #pragma unroll
    for (int sh = 1; sh < 16; sh <<= 1) { int y = __shfl_up(xs, sh); if (lane >= sh) xs += y; }
    wpre[lane] = xs - ws_;
  }
  __syncthreads();
  int excl = wpre[w] + x - s;
  #pragma unroll
  for (int i = 0; i < SCAN_C; i++) {
    int idx = base + i;
    if (idx < n) { int o = excl + loc[i]; offs[idx] = o; cur[idx] = o; }
  }
  if (t == 1023) offs[n] = excl + s;
}

// fill: CSR slot assign + pack input payload {11 bf16 eattr, src} at slot p (one-time scatter)
__global__ __launch_bounds__(256) void fill_kernel(const float* __restrict__ eattr,
                                                   const int* __restrict__ srcA,
                                                   const int* __restrict__ dstA,
                                                   int* __restrict__ cur,
                                                   int* __restrict__ elist,
                                                   uint4* __restrict__ eattrC, int E) {
  __shared__ float sx[2816];
  long long base = (long long)blockIdx.x * 2816;
  for (int i = threadIdx.x; i < 2816; i += 256) {
    long long gi = base + i;
    sx[i] = (gi < (long long)E * 11) ? eattr[gi] : 0.f;
  }
  __syncthreads();
  int e = blockIdx.x * 256 + threadIdx.x;
  if (e >= E) return;
  int p = atomicAdd(&cur[dstA[e]], 1);
  elist[p] = e;
  const float* a = &sx[threadIdx.x * 11];
  unsigned q0 = (unsigned)tobu(a[0]) | ((unsigned)tobu(a[1]) << 16);
  unsigned q1 = (unsigned)tobu(a[2]) | ((unsigned)tobu(a[3]) << 16);
  unsigned q2 = (unsigned)tobu(a[4]) | ((unsigned)tobu(a[5]) << 16);
  unsigned q3 = (unsigned)tobu(a[6]) | ((unsigned)tobu(a[7]) << 16);
  unsigned q4 = (unsigned)tobu(a[8]) | ((unsigned)tobu(a[9]) << 16);
  unsigned q5 = (unsigned)tobu(a[10]);
  eattrC[(size_t)p * 2]     = make_uint4(q0, q1, q2, q3);
  eattrC[(size_t)p * 2 + 1] = make_uint4(q4, q5, (unsigned)srcA[e], 0u);
}

// ---------------- weight prep (+ zero deg + graph bounds) ----------------
// wE per layer (1352 f32): [e1t 22x12][e2t 22x12][e3t 22x12][e4L 22x12][e4G 22x12][attv 32]
__global__ __launch_bounds__(256) void prep_kernel(const float* __restrict__ e1, const float* __restrict__ e2,
                                                   const float* __restrict__ e3, const float* __restrict__ e4,
                                                   const float* __restrict__ attv, const float* __restrict__ convw,
                                                   const float* __restrict__ outw,
                                                   const int* __restrict__ batch,
                                                   float* __restrict__ wE, bf16* __restrict__ Wt,
                                                   bf16* __restrict__ owB, int* __restrict__ gb,
                                                   int* __restrict__ deg) {
  int i = blockIdx.x * blockDim.x + threadIdx.x;
  if (i < N_NODES) deg[i] = 0;
  if (i < 2 * 1352) {
    int l = i / 1352, r = i % 1352;
    float v = 0.f;
    if (r < 264)       { int q = r;        int j = q / 12, k = q % 12; if (k < 11) v = e1[l*242 + k*22 + j]; }
    else if (r < 528)  { int q = r - 264;  int j = q / 12, k = q % 12; if (k < 11) v = e2[l*242 + k*22 + j]; }
    else if (r < 792)  { int q = r - 528;  int j = q / 12, k = q % 12; if (k < 11) v = e3[l*242 + k*22 + j]; }
    else if (r < 1056) { int q = r - 792;  int j = q / 12, k = q % 12; if (k < 11) v = e4[l*484 + j*11 + k]; }
    else if (r < 1320) { int q = r - 1056; int j = q / 12, k = q % 12; if (k < 11) v = e4[l*484 + (22 + j)*11 + k]; }
    else               { int d = r - 1320; v = attv[l*32 + d]; }
    wE[i] = v;
  }
  int t = i - 2 * 1352;
  if (t >= 0 && t < 2 * 32 * 352) {
    int l = t / (32 * 352), q = t % (32 * 352);
    int o = q / 352, dk = q % 352;
    int d = dk / 11, kk = dk % 11;
    float v = 0.f;
    if (o < 30) v = convw[l*10560 + (kk*32 + d)*30 + o];
    Wt[t] = tob(v);
  }
  int u = i - 2 * 1352 - 2 * 32 * 352;
  if (u >= 0 && u < 2048) {
    int l = u >> 10, rem = u & 1023;
    int hf = rem >> 9, rem2 = rem & 511;
    int lane = rem2 >> 3, j = rem2 & 7;
    int k = (lane >> 4) * 8 + j, n = lane & 15;
    owB[u] = tob(outw[l*1024 + k*32 + hf*16 + n]);
  }
  int g = i - 2 * 1352 - 2 * 32 * 352 - 2048;
  if (g >= 0 && g <= N_GR) {
    if (g == N_GR) { gb[g] = N_NODES; }
    else {
      int lo = 0, hi = N_NODES;
      while (lo < hi) { int mid = (lo + hi) >> 1; if (batch[mid] < g) lo = mid + 1; else hi = mid; }
      gb[g] = lo;
    }
  }
}

// ---------------- fused embedding + h_proj(layer 0) ----------------
__global__ __launch_bounds__(256) void emb_hproj_kernel(const float* __restrict__ x, const float* __restrict__ w,
                                                        const float* __restrict__ b, const float* __restrict__ w1,
                                                        float* __restrict__ h, float* __restrict__ hp,
                                                        unsigned short* __restrict__ hpb, int N) {
  __shared__ float semb[16 * 32];
  __shared__ float sw1[32 * 32];
  __shared__ float sb[32];
  __shared__ float sx[8][16];
  __shared__ float sh[8][33];
  int tid = threadIdx.x;
  for (int i = tid; i < 16 * 32; i += 256) semb[i] = w[i];
  for (int i = tid; i < 32 * 32; i += 256) sw1[i] = w1[i];
  if (tid < 32) sb[tid] = b[tid];
  int nb = blockIdx.x * 8;
  if (tid < 128) {
    int n = nb + (tid >> 4), k = tid & 15;
    sx[tid >> 4][k] = (n < N) ? x[(size_t)n * 16 + k] : 0.f;
  }
  __syncthreads();
  int grp = tid >> 5, d = tid & 31;
  int n = nb + grp;
  float acc = sb[d];
  #pragma unroll
  for (int k = 0; k < 16; k++) acc += sx[grp][k] * semb[k*32 + d];
  sh[grp][d] = acc;
  if (n < N) h[(size_t)n * 32 + d] = acc;
  __syncthreads();
  float hpv = 0.f;
  #pragma unroll
  for (int k = 0; k < 32; k++) hpv += sh[grp][k] * sw1[k*32 + d];
  if (n < N) {
    hp[(size_t)n * 32 + d] = hpv;
    hpb[(size_t)n * 32 + d] = tobu(hpv);
  }
}

// ---------------- edge MLP + raw attention: one thread per CSR slot, fully streaming ----------------
__device__ __forceinline__ void loadw12(const float4* base, int idx3, float* w) {
  float4 a = base[idx3], b = base[idx3 + 1], c = base[idx3 + 2];
  w[0]=a.x; w[1]=a.y; w[2]=a.z; w[3]=a.w;
  w[4]=b.x; w[5]=b.y; w[6]=b.z; w[7]=b.w;
  w[8]=c.x; w[9]=c.y; w[10]=c.z; w[11]=c.w;
}

__global__ __launch_bounds__(256) void edge_kernel(const uint4* __restrict__ eattrC,
                                                   const unsigned short* __restrict__ hpb,
                                                   const float* __restrict__ wEl,
                                                   uint4* __restrict__ pay, int E) {
  const float4* w4 = (const float4*)wEl;
  int p = blockIdx.x * blockDim.x + threadIdx.x;
  if (p >= E) return;
  uint4 c0 = eattrC[(size_t)p * 2];
  uint4 c1 = eattrC[(size_t)p * 2 + 1];
  float a[11];
  a[0] = b2f((unsigned short)c0.x); a[1] = b2f((unsigned short)(c0.x >> 16));
  a[2] = b2f((unsigned short)c0.y); a[3] = b2f((unsigned short)(c0.y >> 16));
  a[4] = b2f((unsigned short)c0.z); a[5] = b2f((unsigned short)(c0.z >> 16));
  a[6] = b2f((unsigned short)c0.w); a[7] = b2f((unsigned short)(c0.w >> 16));
  a[8] = b2f((unsigned short)c1.x); a[9] = b2f((unsigned short)(c1.x >> 16));
  a[10] = b2f((unsigned short)c1.y);
  int s = (int)c1.z;
  float acc[11];
  #pragma unroll
  for (int k = 0; k < 11; k++) acc[k] = 0.f;
  for (int j = 0; j < 22; j++) {
    float w[12];
    loadw12(w4, j*3, w);
    float l1 = 0.f;
    #pragma unroll
    for (int k = 0; k < 11; k++) l1 += a[k] * w[k];
    loadw12(w4, 66 + j*3, w);
    float l2 = 0.f;
    #pragma unroll
    for (int k = 0; k < 11; k++) l2 += a[k] * w[k];
    loadw12(w4, 132 + j*3, w);
    float l3 = 0.f;
    #pragma unroll
    for (int k = 0; k < 11; k++) l3 += a[k] * w[k];
    float gg = tanh_fast(l2) * tanh_fast(l3);
    l1 = fmaxf(l1, 0.f);
    float wl[12], wg[12];
    loadw12(w4, 198 + j*3, wl);
    loadw12(w4, 264 + j*3, wg);
    #pragma unroll
    for (int k = 0; k < 11; k++) acc[k] += l1*wl[k] + gg*wg[k];
  }
  const float* av = wEl + 1320;
  float mean = 0.f;
  #pragma unroll
  for (int k = 0; k < 11; k++) { acc[k] = fmaxf(acc[k], 0.f); mean += acc[k]; }
  mean *= (1.f / 11.f);
  const uint2* hb = (const uint2*)(hpb + (size_t)s * 32);
  float dot = 0.f;
  #pragma unroll
  for (int q = 0; q < 8; q++) {
    uint2 hv = hb[q];
    dot += b2f((unsigned short)hv.x) * av[q*4+0] + b2f((unsigned short)(hv.x >> 16)) * av[q*4+1]
         + b2f((unsigned short)hv.y) * av[q*4+2] + b2f((unsigned short)(hv.y >> 16)) * av[q*4+3];
  }
  float raw = mean * dot;
  unsigned q[6];
  #pragma unroll
  for (int m = 0; m < 5; m++)
    q[m] = (unsigned)tobu(acc[2*m]) | ((unsigned)tobu(acc[2*m+1]) << 16);
  q[5] = (unsigned)tobu(acc[10]);
  pay[(size_t)p * 2]     = make_uint4(q[0], q[1], q[2], q[3]);
  pay[(size_t)p * 2 + 1] = make_uint4(q[4], q[5], __float_as_uint(raw), (unsigned)s);
}

// ---------------- per-node aggregation: softmax scan then branch-free reduction ----------------
__device__ __forceinline__ void unpack_pay(uint4 p0, uint4 p1, float* ev) {
  ev[0] = b2f((unsigned short)p0.x); ev[1] = b2f((unsigned short)(p0.x >> 16));
  ev[2] = b2f((unsigned short)p0.y); ev[3] = b2f((unsigned short)(p0.y >> 16));
  ev[4] = b2f((unsigned short)p0.z); ev[5] = b2f((unsigned short)(p0.z >> 16));
  ev[6] = b2f((unsigned short)p0.w); ev[7] = b2f((unsigned short)(p0.w >> 16));
  ev[8] = b2f((unsigned short)p1.x); ev[9] = b2f((unsigned short)(p1.x >> 16));
  ev[10] = b2f((unsigned short)p1.y);
}

__global__ __launch_bounds__(256) void node_kernel(const int* __restrict__ offs, const int* __restrict__ elist,
                                                   const uint4* __restrict__ pay,
                                                   const unsigned short* __restrict__ hpb,
                                                   bf16* __restrict__ Abuf, float* __restrict__ atts, int N) {
  int wid = threadIdx.x >> 6, lane = threadIdx.x & 63;
  int half = lane >> 5, d = lane & 31;
  int n = blockIdx.x * 4 + wid;
  if (n >= N_PAD) return;
  int beg = 0, deg = 0;
  if (n < N) { beg = offs[n]; deg = offs[n + 1] - beg; }
  const float* payf = (const float*)pay;

  float M, inv;
  float einv_reg = 0.f;
  bool fast = (deg <= 64);
  if (fast) {
    float r = (lane < deg) ? payf[(size_t)(beg + lane) * 8 + 6] : -1e30f;
    float mm = r;
    #pragma unroll
    for (int sh = 1; sh < 64; sh <<= 1) mm = fmaxf(mm, __shfl_xor(mm, sh));
    M = mm;
    float ex = (lane < deg) ? __expf(r - M) : 0.f;
    float ss = ex;
    #pragma unroll
    for (int sh = 1; sh < 64; sh <<= 1) ss += __shfl_xor(ss, sh);
    inv = 1.f / (ss + 1e-16f);
    einv_reg = ex * inv;
    if (lane < deg) atts[elist[beg + lane]] = einv_reg;
  } else {
    float m_l = -1e30f;
    for (int jj = lane; jj < deg; jj += 64)
      m_l = fmaxf(m_l, payf[(size_t)(beg + jj) * 8 + 6]);
    #pragma unroll
    for (int sh = 1; sh < 64; sh <<= 1) m_l = fmaxf(m_l, __shfl_xor(m_l, sh));
    M = m_l;
    float s_l = 0.f;
    for (int jj = lane; jj < deg; jj += 64)
      s_l += __expf(payf[(size_t)(beg + jj) * 8 + 6] - M);
    #pragma unroll
    for (int sh = 1; sh < 64; sh <<= 1) s_l += __shfl_xor(s_l, sh);
    inv = 1.f / (s_l + 1e-16f);
    for (int jj = lane; jj < deg; jj += 64) {
      float r = payf[(size_t)(beg + jj) * 8 + 6];
      atts[elist[beg + jj]] = __expf(r - M) * inv;
    }
  }

  float agg[11];
  #pragma unroll
  for (int k = 0; k < 11; k++) agg[k] = 0.f;

  int j = half;
  for (; j + 2 < deg; j += 4) {
    uint4 a0 = pay[(size_t)(beg + j) * 2],     a1 = pay[(size_t)(beg + j) * 2 + 1];
    uint4 b0 = pay[(size_t)(beg + j + 2) * 2], b1 = pay[(size_t)(beg + j + 2) * 2 + 1];
    float xa = b2f(hpb[(size_t)(int)a1.w * 32 + d]);
    float xb = b2f(hpb[(size_t)(int)b1.w * 32 + d]);
    float ca = fast ? (1.f + __shfl(einv_reg, j))
                    : (1.f + __expf(__uint_as_float(a1.z) - M) * inv);
    float cb = fast ? (1.f + __shfl(einv_reg, j + 2))
                    : (1.f + __expf(__uint_as_float(b1.z) - M) * inv);
    float cxa = ca * xa, cxb = cb * xb;
    float eva[11], evb[11];
    unpack_pay(a0, a1, eva);
    unpack_pay(b0, b1, evb);
    #pragma unroll
    for (int k = 0; k < 11; k++) agg[k] += eva[k] * cxa + evb[k] * cxb;
  }
  for (; j < deg; j += 2) {
    uint4 q0 = pay[(size_t)(beg + j) * 2], q1 = pay[(size_t)(beg + j) * 2 + 1];
    float xs = b2f(hpb[(size_t)(int)q1.w * 32 + d]);
    float c = fast ? (1.f + __shfl(einv_reg, j))
                   : (1.f + __expf(__uint_as_float(q1.z) - M) * inv);
    float cx = c * xs;
    float ev[11];
    unpack_pay(q0, q1, ev);
    #pragma unroll
    for (int k = 0; k < 11; k++) agg[k] += ev[k] * cx;
  }

  #pragma unroll
  for (int k = 0; k < 11; k++) agg[k] += __shfl_xor(agg[k], 32);

  if (half == 0) {
    bf16* arow = Abuf + (size_t)n * 352 + d * 11;
    #pragma unroll
    for (int k = 0; k < 11; k++) arow[k] = tob(agg[k]);
  }
}

// ---------------- fused conv GEMM + epilogue (+ optional next-layer h_proj) ----------------
__global__ __launch_bounds__(128) void convfused_kernel(const short* __restrict__ A, const short* __restrict__ Wt,
                                                        const short* __restrict__ owB,
                                                        const float* __restrict__ hp, float* __restrict__ h,
                                                        const float* __restrict__ convb,
                                                        const float* __restrict__ s1w, const float* __restrict__ s1b,
                                                        const float* __restrict__ s2w, const float* __restrict__ s2b,
                                                        const float* __restrict__ outb,
                                                        const float* __restrict__ initw_next,
                                                        float* __restrict__ hp_out, unsigned short* __restrict__ hpb_out,
                                                        int N) {
  __shared__ short slo[32][40];
  __shared__ float sdelta[32][36];
  __shared__ float sskipw[128];
  __shared__ float sskipb[4];
  __shared__ float scb[32];
  __shared__ float sob[32];
  __shared__ float sw1[1024];
  int tid = threadIdx.x;
  if (tid < 64) sskipw[tid] = s1w[tid];
  if (tid >= 64 && tid < 128) sskipw[tid] = s2w[tid - 64];
  if (tid < 32) sob[tid] = outb[tid];
  if (tid >= 32 && tid < 64) scb[tid - 32] = (tid - 32 < 30) ? convb[tid - 32] : 0.f;
  if (tid >= 96 && tid < 100) sskipb[tid - 96] = (tid < 98) ? s1b[tid - 96] : s2b[tid - 98];
  if (initw_next) {
    for (int i = tid; i < 1024; i += 128) sw1[i] = initw_next[i];
  }
  __syncthreads();

  int wave = tid >> 6, lane = tid & 63;
  int r16 = lane & 15, kq = lane >> 4;
  int mbase = blockIdx.x * 32 + wave * 16;

  const short* arow = A + (size_t)(mbase + r16) * 352 + kq * 8;
  const short* b0p = Wt + (size_t)r16 * 352 + kq * 8;
  const short* b1p = b0p + 16 * 352;
  f32x4v acc0 = {0.f, 0.f, 0.f, 0.f}, acc1 = {0.f, 0.f, 0.f, 0.f};
  #pragma unroll
  for (int ks = 0; ks < 11; ks++) {
    bf16x8 af = *(const bf16x8*)(arow + ks * 32);
    bf16x8 b0 = *(const bf16x8*)(b0p + ks * 32);
    bf16x8 b1 = *(const bf16x8*)(b1p + ks * 32);
    acc0 = __builtin_amdgcn_mfma_f32_16x16x32_bf16(af, b0, acc0, 0, 0, 0);
    acc1 = __builtin_amdgcn_mfma_f32_16x16x32_bf16(af, b1, acc1, 0, 0, 0);
  }
  #pragma unroll
  for (int r = 0; r < 4; r++) {
    int row = wave * 16 + kq * 4 + r;
    slo[row][r16] = (short)tobu(fmaxf(acc0[r] + scb[r16], 0.f));
    if (r16 < 14) slo[row][16 + r16] = (short)tobu(fmaxf(acc1[r] + scb[16 + r16], 0.f));
  }
  __syncthreads();

  if (tid < 64) {
    int row = tid >> 1, jx = tid & 1;
    int grow = blockIdx.x * 32 + row;
    float a1 = sskipb[jx], a2 = sskipb[2 + jx];
    if (grow < N) {
      const float* hr = hp + (size_t)grow * 32;
      #pragma unroll
      for (int dd = 0; dd < 32; dd++) {
        float hv = hr[dd];
        a1 += hv * sskipw[dd*2 + jx];
        a2 += hv * sskipw[64 + dd*2 + jx];
      }
    }
    slo[row][30 + jx] = (short)tobu(tanh_fast(a1) * tanh_fast(a2));
  }
  __syncthreads();

  bf16x8 a2f = *(const bf16x8*)&slo[wave * 16 + r16][kq * 8];
  bf16x8 bo0 = *(const bf16x8*)(owB + lane * 8);
  bf16x8 bo1 = *(const bf16x8*)(owB + 512 + lane * 8);
  f32x4v d0 = {0.f, 0.f, 0.f, 0.f}, d1 = {0.f, 0.f, 0.f, 0.f};
  d0 = __builtin_amdgcn_mfma_f32_16x16x32_bf16(a2f, bo0, d0, 0, 0, 0);
  d1 = __builtin_amdgcn_mfma_f32_16x16x32_bf16(a2f, bo1, d1, 0, 0, 0);
  #pragma unroll
  for (int r = 0; r < 4; r++) {
    int row = wave * 16 + kq * 4 + r;
    sdelta[row][r16] = d0[r] + sob[r16];
    sdelta[row][16 + r16] = d1[r] + sob[16 + r16];
  }
  __syncthreads();

  int row = tid >> 2, col0 = (tid & 3) * 8;
  int grow = blockIdx.x * 32 + row;
  if (grow < N) {
    float* hr = h + (size_t)grow * 32 + col0;
    float4 ha = *(float4*)hr;
    float4 hb = *(float4*)(hr + 4);
    float4 da = *(float4*)&sdelta[row][col0];
    float4 db = *(float4*)&sdelta[row][col0 + 4];
    ha.x += da.x; ha.y += da.y; ha.z += da.z; ha.w += da.w;
    hb.x += db.x; hb.y += db.y; hb.z += db.z; hb.w += db.w;
    *(float4*)hr = ha;
    *(float4*)(hr + 4) = hb;
    *(float4*)&sdelta[row][col0] = ha;
    *(float4*)&sdelta[row][col0 + 4] = hb;
  }
  if (initw_next) {
    __syncthreads();
    if (grow < N) {
      float o[8];
      #pragma unroll
      for (int c = 0; c < 8; c++) o[c] = 0.f;
      #pragma unroll
      for (int k = 0; k < 32; k++) {
        float hv = sdelta[row][k];
        #pragma unroll
        for (int c = 0; c < 8; c++) o[c] += hv * sw1[k*32 + col0 + c];
      }
      float* hpo = hp_out + (size_t)grow * 32 + col0;
      unsigned short* hbo = hpb_out + (size_t)grow * 32 + col0;
      #pragma unroll
      for (int c = 0; c < 8; c++) { hpo[c] = o[c]; hbo[c] = tobu(o[c]); }
    }
  }
}

// ---------------- fused pool / outh / final head ----------------
__global__ __launch_bounds__(256) void pool2_kernel(const float* __restrict__ h, const int* __restrict__ gb,
                                                    const float* __restrict__ fw, const float* __restrict__ fb,
                                                    float* __restrict__ out0, float* __restrict__ outh) {
  __shared__ float part[8][32];
  __shared__ float pooled[32];
  int g = blockIdx.x;
  int s = gb[g], e = gb[g + 1];
  int grp = threadIdx.x >> 5, d = threadIdx.x & 31;
  float acc = 0.f;
  for (int n = s + grp; n < e; n += 8) {
    float v = h[(size_t)n * 32 + d];
    outh[(size_t)n * 32 + d] = v;
    acc += v;
  }
  part[grp][d] = acc;
  __syncthreads();
  if (threadIdx.x < 32) {
    float sum = 0.f;
    #pragma unroll
    for (int i = 0; i < 8; i++) sum += part[i][d];
    pooled[d] = sum / fmaxf((float)(e - s), 1.f);
  }
  __syncthreads();
  if (threadIdx.x < 32) {
    int jx = threadIdx.x;
    float o = fb[jx];
    #pragma unroll
    for (int dd = 0; dd < 32; dd++) o += pooled[dd] * fw[dd*32 + jx];
    out0[g * 32 + jx] = o;
  }
}

extern "C" void kernel_launch(void* const* d_in, const int* in_sizes, int n_in,
                              void* d_out, int out_size, void* d_ws, size_t ws_size,
                              hipStream_t stream) {
  (void)in_sizes; (void)n_in; (void)out_size; (void)ws_size;
  const float* x      = (const float*)d_in[0];
  const float* eattr  = (const float*)d_in[1];
  const int* eidx     = (const int*)d_in[2];
  const int* batch    = (const int*)d_in[3];
  const float* emb_w  = (const float*)d_in[4];
  const float* emb_b  = (const float*)d_in[5];
  const float* init_w = (const float*)d_in[6];
  const float* e1w    = (const float*)d_in[7];
  const float* e2w    = (const float*)d_in[8];
  const float* e3w    = (const float*)d_in[9];
  const float* e4w    = (const float*)d_in[10];
  const float* convw  = (const float*)d_in[11];
  const float* convb  = (const float*)d_in[12];
  const float* attv   = (const float*)d_in[13];
  const float* s1w    = (const float*)d_in[14];
  const float* s1b    = (const float*)d_in[15];
  const float* s2w    = (const float*)d_in[16];
  const float* s2b    = (const float*)d_in[17];
  const float* outw   = (const float*)d_in[18];
  const float* outb   = (const float*)d_in[19];
  const float* finw   = (const float*)d_in[20];
  const float* finb   = (const float*)d_in[21];

  char* ws = (char*)d_ws;
  size_t off = 0;
  auto take = [&](size_t bytes) -> char* {
    char* p = ws + off;
    off += (bytes + 255) & ~(size_t)255;
    return p;
  };
  float* h    = (float*)take((size_t)N_NODES * 32 * 4);
  float* hp   = (float*)take((size_t)N_NODES * 32 * 4);
  unsigned short* hpb = (unsigned short*)take((size_t)N_NODES * 32 * 2);
  uint4* pay  = (uint4*)take((size_t)N_EDGES * 32);
  uint4* eattrC = (uint4*)take((size_t)N_EDGES * 32);
  bf16*  Abuf = (bf16*)take((size_t)N_PAD * 352 * 2);
  int*   deg  = (int*)take((size_t)N_NODES * 4);
  int*   offs = (int*)take((size_t)(N_NODES + 1) * 4);
  int*   cur  = (int*)take((size_t)N_NODES * 4);
  int*   elist= (int*)take((size_t)N_EDGES * 4);
  int*   gb   = (int*)take((size_t)(N_GR + 1) * 4);
  float* wE   = (float*)take((size_t)2 * 1352 * 4);
  bf16*  Wt   = (bf16*)take((size_t)2 * 32 * 352 * 2);
  bf16*  owB  = (bf16*)take((size_t)2048 * 2);

  float* out0 = (float*)d_out;
  float* outh = out0 + N_GR * 32;
  float* outa = outh + (size_t)N_NODES * 32;

  const int* srcA = eidx;
  const int* dstA = eidx + N_EDGES;

  prep_kernel<<<107, 256, 0, stream>>>(e1w, e2w, e3w, e4w, attv, convw, outw, batch, wE, Wt, owB, gb, deg);
  hist_kernel<<<(N_EDGES + 255) / 256, 256, 0, stream>>>(dstA, deg, N_EDGES);
  scan_kernel<<<1, 1024, 0, stream>>>(deg, offs, cur, N_NODES);
  fill_kernel<<<(N_EDGES + 255) / 256, 256, 0, stream>>>(eattr, srcA, dstA, cur, elist, eattrC, N_EDGES);
  emb_hproj_kernel<<<(N_NODES + 7) / 8, 256, 0, stream>>>(x, emb_w, emb_b, init_w, h, hp, hpb, N_NODES);

  for (int l = 0; l < 2; l++) {
    edge_kernel<<<(N_EDGES + 255) / 256, 256, 0, stream>>>(
        eattrC, hpb, wE + l * 1352, pay, N_EDGES);
    node_kernel<<<N_PAD / 4, 256, 0, stream>>>(offs, elist, pay, hpb,
                                               Abuf, outa + (size_t)l * N_EDGES, N_NODES);
    convfused_kernel<<<N_PAD / 32, 128, 0, stream>>>(
        (const short*)Abuf, (const short*)Wt + (size_t)l * 32 * 352, (const short*)owB + (size_t)l * 1024,
        hp, h, convb + l * 30, s1w + l * 64, s1b + l * 2, s2w + l * 64, s2b + l * 2,
        outb + l * 32,
        (l == 0) ? (init_w + 1024) : nullptr, hp, hpb, N_NODES);
  }

  pool2_kernel<<<N_GR, 256, 0, stream>>>(h, gb, finw, finb, out0, outh);
}

// Round 13
// 241.470 us; speedup vs baseline: 1.0558x; 1.0558x over previous
//
#include <hip/hip_runtime.h>
#include <hip/hip_bf16.h>

typedef __hip_bfloat16 bf16;
using f32x4v = __attribute__((ext_vector_type(4))) float;
using bf16x8 = __attribute__((ext_vector_type(8))) short;

#define N_NODES 25000
#define N_PAD   25024   // multiple of 32 for conv kernel tiles
#define N_EDGES 400000
#define N_GR    100
#define SCAN_C  25      // 1024 * 25 = 25600 >= N_NODES

__device__ __forceinline__ bf16 tob(float v) { return __float2bfloat16(v); }
__device__ __forceinline__ unsigned short tobu(float v) {
  union { bf16 b; unsigned short u; } c; c.b = __float2bfloat16(v); return c.u;
}
__device__ __forceinline__ float b2f(unsigned short u) { return __uint_as_float(((unsigned)u) << 16); }
// clamp-free tanh: 1 - 2/(e^{2x}+1); inf-safe
__device__ __forceinline__ float tanh_fast(float x) {
  float e = __expf(2.f * x);
  return 1.f - 2.f * __builtin_amdgcn_rcpf(e + 1.f);
}

// ---------------- CSR build ----------------
__global__ __launch_bounds__(256) void hist_kernel(const int* __restrict__ dst, int* __restrict__ deg, int E) {
  int e = blockIdx.x * blockDim.x + threadIdx.x;
  if (e < E) atomicAdd(&deg[dst[e]], 1);
}

// one-pass scan: thread-local 25-chunk scan in registers + block scan of totals
__global__ __launch_bounds__(1024) void scan_kernel(const int* __restrict__ deg, int* __restrict__ offs,
                                                    int* __restrict__ cur, int n) {
  __shared__ int wsum[16];
  __shared__ int wpre[16];
  int t = threadIdx.x, lane = t & 63, w = t >> 6;
  int base = t * SCAN_C;
  int loc[SCAN_C];
  int s = 0;
  #pragma unroll
  for (int i = 0; i < SCAN_C; i++) {
    int idx = base + i;
    int v = (idx < n) ? deg[idx] : 0;
    loc[i] = s; s += v;
  }
  int x = s;
  #pragma unroll
  for (int sh = 1; sh < 64; sh <<= 1) { int y = __shfl_up(x, sh); if (lane >= sh) x += y; }
  if (lane == 63) wsum[w] = x;
  __syncthreads();
  if (w == 0 && lane < 16) {
    int ws_ = wsum[lane], xs = ws_;
    #pragma unroll
    for (int sh = 1; sh < 16; sh <<= 1) { int y = __shfl_up(xs, sh); if (lane >= sh) xs += y; }
    wpre[lane] = xs - ws_;
  }
  __syncthreads();
  int excl = wpre[w] + x - s;
  #pragma unroll
  for (int i = 0; i < SCAN_C; i++) {
    int idx = base + i;
    if (idx < n) { int o = excl + loc[i]; offs[idx] = o; cur[idx] = o; }
  }
  if (t == 1023) offs[n] = excl + s;
}

// ---------------- weight prep (+ zero deg + graph bounds) ----------------
// wE per layer (1352 f32): [e1t 22x12][e2t 22x12][e3t 22x12][e4L 22x12][e4G 22x12][attv 32]
__global__ __launch_bounds__(256) void prep_kernel(const float* __restrict__ e1, const float* __restrict__ e2,
                                                   const float* __restrict__ e3, const float* __restrict__ e4,
                                                   const float* __restrict__ attv, const float* __restrict__ convw,
                                                   const float* __restrict__ outw,
                                                   const int* __restrict__ batch,
                                                   float* __restrict__ wE, bf16* __restrict__ Wt,
                                                   bf16* __restrict__ owB, int* __restrict__ gb,
                                                   int* __restrict__ deg) {
  int i = blockIdx.x * blockDim.x + threadIdx.x;
  if (i < N_NODES) deg[i] = 0;
  if (i < 2 * 1352) {
    int l = i / 1352, r = i % 1352;
    float v = 0.f;
    if (r < 264)       { int q = r;        int j = q / 12, k = q % 12; if (k < 11) v = e1[l*242 + k*22 + j]; }
    else if (r < 528)  { int q = r - 264;  int j = q / 12, k = q % 12; if (k < 11) v = e2[l*242 + k*22 + j]; }
    else if (r < 792)  { int q = r - 528;  int j = q / 12, k = q % 12; if (k < 11) v = e3[l*242 + k*22 + j]; }
    else if (r < 1056) { int q = r - 792;  int j = q / 12, k = q % 12; if (k < 11) v = e4[l*484 + j*11 + k]; }
    else if (r < 1320) { int q = r - 1056; int j = q / 12, k = q % 12; if (k < 11) v = e4[l*484 + (22 + j)*11 + k]; }
    else               { int d = r - 1320; v = attv[l*32 + d]; }
    wE[i] = v;
  }
  int t = i - 2 * 1352;
  if (t >= 0 && t < 2 * 32 * 352) {
    int l = t / (32 * 352), q = t % (32 * 352);
    int o = q / 352, dk = q % 352;
    int d = dk / 11, kk = dk % 11;
    float v = 0.f;
    if (o < 30) v = convw[l*10560 + (kk*32 + d)*30 + o];
    Wt[t] = tob(v);
  }
  int u = i - 2 * 1352 - 2 * 32 * 352;
  if (u >= 0 && u < 2048) {
    int l = u >> 10, rem = u & 1023;
    int hf = rem >> 9, rem2 = rem & 511;
    int lane = rem2 >> 3, j = rem2 & 7;
    int k = (lane >> 4) * 8 + j, n = lane & 15;
    owB[u] = tob(outw[l*1024 + k*32 + hf*16 + n]);
  }
  int g = i - 2 * 1352 - 2 * 32 * 352 - 2048;
  if (g >= 0 && g <= N_GR) {
    if (g == N_GR) { gb[g] = N_NODES; }
    else {
      int lo = 0, hi = N_NODES;
      while (lo < hi) { int mid = (lo + hi) >> 1; if (batch[mid] < g) lo = mid + 1; else hi = mid; }
      gb[g] = lo;
    }
  }
}

// ---------------- fused embedding + h_proj(layer 0) ----------------
__global__ __launch_bounds__(256) void emb_hproj_kernel(const float* __restrict__ x, const float* __restrict__ w,
                                                        const float* __restrict__ b, const float* __restrict__ w1,
                                                        float* __restrict__ h, float* __restrict__ hp,
                                                        unsigned short* __restrict__ hpb, int N) {
  __shared__ float semb[16 * 32];
  __shared__ float sw1[32 * 32];
  __shared__ float sb[32];
  __shared__ float sx[8][16];
  __shared__ float sh[8][33];
  int tid = threadIdx.x;
  for (int i = tid; i < 16 * 32; i += 256) semb[i] = w[i];
  for (int i = tid; i < 32 * 32; i += 256) sw1[i] = w1[i];
  if (tid < 32) sb[tid] = b[tid];
  int nb = blockIdx.x * 8;
  if (tid < 128) {
    int n = nb + (tid >> 4), k = tid & 15;
    sx[tid >> 4][k] = (n < N) ? x[(size_t)n * 16 + k] : 0.f;
  }
  __syncthreads();
  int grp = tid >> 5, d = tid & 31;
  int n = nb + grp;
  float acc = sb[d];
  #pragma unroll
  for (int k = 0; k < 16; k++) acc += sx[grp][k] * semb[k*32 + d];
  sh[grp][d] = acc;
  if (n < N) h[(size_t)n * 32 + d] = acc;
  __syncthreads();
  float hpv = 0.f;
  #pragma unroll
  for (int k = 0; k < 32; k++) hpv += sh[grp][k] * sw1[k*32 + d];
  if (n < N) {
    hp[(size_t)n * 32 + d] = hpv;
    hpb[(size_t)n * 32 + d] = tobu(hpv);
  }
}

// ---------------- edge MLP for BOTH layers in one pass -> CSR payloads with {ea, mean, src} ----------------
__device__ __forceinline__ void loadw12(const float4* base, int idx3, float* w) {
  float4 a = base[idx3], b = base[idx3 + 1], c = base[idx3 + 2];
  w[0]=a.x; w[1]=a.y; w[2]=a.z; w[3]=a.w;
  w[4]=b.x; w[5]=b.y; w[6]=b.z; w[7]=b.w;
  w[8]=c.x; w[9]=c.y; w[10]=c.z; w[11]=c.w;
}

__global__ __launch_bounds__(256) void edge_mlp_kernel(const float* __restrict__ eattr,
                                                       const int* __restrict__ srcA,
                                                       const int* __restrict__ dstA,
                                                       int* __restrict__ cur,
                                                       int* __restrict__ elist,
                                                       const float* __restrict__ wE0,
                                                       const float* __restrict__ wE1,
                                                       uint4* __restrict__ pay0,
                                                       uint4* __restrict__ pay1, int E) {
  const float4* wa = (const float4*)wE0;
  const float4* wb = (const float4*)wE1;
  int e = blockIdx.x * blockDim.x + threadIdx.x;
  bool live = e < E;
  float a[11], acc0[11], acc1[11];
  #pragma unroll
  for (int k = 0; k < 11; k++) {
    a[k] = live ? eattr[(size_t)e*11 + k] : 0.f;
    acc0[k] = 0.f; acc1[k] = 0.f;
  }
  // one-time CSR slot assignment, overlapped with the MLP compute
  int pp = 0, s = 0;
  if (live) {
    s = srcA[e];
    pp = atomicAdd(&cur[dstA[e]], 1);
    elist[pp] = e;
  }
  for (int j = 0; j < 22; j++) {
    float wA[12], wB[12], wC[12];
    // layer 0 first stage
    loadw12(wa, j*3, wA);
    loadw12(wa, 66 + j*3, wB);
    loadw12(wa, 132 + j*3, wC);
    float l1a = 0.f, l2a = 0.f, l3a = 0.f;
    #pragma unroll
    for (int k = 0; k < 11; k++) { l1a += a[k]*wA[k]; l2a += a[k]*wB[k]; l3a += a[k]*wC[k]; }
    // layer 1 first stage (independent chain -> ILP)
    loadw12(wb, j*3, wA);
    loadw12(wb, 66 + j*3, wB);
    loadw12(wb, 132 + j*3, wC);
    float l1b = 0.f, l2b = 0.f, l3b = 0.f;
    #pragma unroll
    for (int k = 0; k < 11; k++) { l1b += a[k]*wA[k]; l2b += a[k]*wB[k]; l3b += a[k]*wC[k]; }
    float gga = tanh_fast(l2a) * tanh_fast(l3a);
    float ggb = tanh_fast(l2b) * tanh_fast(l3b);
    l1a = fmaxf(l1a, 0.f);
    l1b = fmaxf(l1b, 0.f);
    // layer 0 second stage
    loadw12(wa, 198 + j*3, wA);
    loadw12(wa, 264 + j*3, wB);
    #pragma unroll
    for (int k = 0; k < 11; k++) acc0[k] += l1a*wA[k] + gga*wB[k];
    // layer 1 second stage
    loadw12(wb, 198 + j*3, wA);
    loadw12(wb, 264 + j*3, wB);
    #pragma unroll
    for (int k = 0; k < 11; k++) acc1[k] += l1b*wA[k] + ggb*wB[k];
  }
  if (!live) return;
  float mean0 = 0.f, mean1 = 0.f;
  #pragma unroll
  for (int k = 0; k < 11; k++) {
    acc0[k] = fmaxf(acc0[k], 0.f); mean0 += acc0[k];
    acc1[k] = fmaxf(acc1[k], 0.f); mean1 += acc1[k];
  }
  mean0 *= (1.f / 11.f);
  mean1 *= (1.f / 11.f);
  unsigned q[6];
  #pragma unroll
  for (int m = 0; m < 5; m++)
    q[m] = (unsigned)tobu(acc0[2*m]) | ((unsigned)tobu(acc0[2*m+1]) << 16);
  q[5] = (unsigned)tobu(acc0[10]);
  pay0[(size_t)pp * 2]     = make_uint4(q[0], q[1], q[2], q[3]);
  pay0[(size_t)pp * 2 + 1] = make_uint4(q[4], q[5], __float_as_uint(mean0), (unsigned)s);
  #pragma unroll
  for (int m = 0; m < 5; m++)
    q[m] = (unsigned)tobu(acc1[2*m]) | ((unsigned)tobu(acc1[2*m+1]) << 16);
  q[5] = (unsigned)tobu(acc1[10]);
  pay1[(size_t)pp * 2]     = make_uint4(q[0], q[1], q[2], q[3]);
  pay1[(size_t)pp * 2 + 1] = make_uint4(q[4], q[5], __float_as_uint(mean1), (unsigned)s);
}

// ---------------- per-layer raw attention: raw = mean * (hp . attv), overwrites .z ----------------
__global__ __launch_bounds__(256) void edge_raw_kernel(uint4* __restrict__ pay,
                                                       const unsigned short* __restrict__ hpb,
                                                       const float* __restrict__ attvl, int E) {
  int p = blockIdx.x * blockDim.x + threadIdx.x;
  if (p >= E) return;
  uint4 m1 = pay[(size_t)p * 2 + 1];
  float mean = __uint_as_float(m1.z);
  int s = (int)m1.w;
  const uint2* hb = (const uint2*)(hpb + (size_t)s * 32);
  float dot = 0.f;
  #pragma unroll
  for (int q = 0; q < 8; q++) {
    uint2 hv = hb[q];
    dot += b2f((unsigned short)hv.x) * attvl[q*4+0] + b2f((unsigned short)(hv.x >> 16)) * attvl[q*4+1]
         + b2f((unsigned short)hv.y) * attvl[q*4+2] + b2f((unsigned short)(hv.y >> 16)) * attvl[q*4+3];
  }
  ((float*)pay)[(size_t)p * 8 + 6] = mean * dot;
}

// ---------------- per-node aggregation: softmax scan then branch-free reduction (r7 verbatim) ----------------
__device__ __forceinline__ void unpack_pay(uint4 p0, uint4 p1, float* ev) {
  ev[0] = b2f((unsigned short)p0.x); ev[1] = b2f((unsigned short)(p0.x >> 16));
  ev[2] = b2f((unsigned short)p0.y); ev[3] = b2f((unsigned short)(p0.y >> 16));
  ev[4] = b2f((unsigned short)p0.z); ev[5] = b2f((unsigned short)(p0.z >> 16));
  ev[6] = b2f((unsigned short)p0.w); ev[7] = b2f((unsigned short)(p0.w >> 16));
  ev[8] = b2f((unsigned short)p1.x); ev[9] = b2f((unsigned short)(p1.x >> 16));
  ev[10] = b2f((unsigned short)p1.y);
}

__global__ __launch_bounds__(256) void node_kernel(const int* __restrict__ offs, const int* __restrict__ elist,
                                                   const uint4* __restrict__ pay,
                                                   const unsigned short* __restrict__ hpb,
                                                   bf16* __restrict__ Abuf, float* __restrict__ atts, int N) {
  int wid = threadIdx.x >> 6, lane = threadIdx.x & 63;
  int half = lane >> 5, d = lane & 31;
  int n = blockIdx.x * 4 + wid;
  if (n >= N_PAD) return;
  int beg = 0, deg = 0;
  if (n < N) { beg = offs[n]; deg = offs[n + 1] - beg; }
  const float* payf = (const float*)pay;

  float M, inv;
  float einv_reg = 0.f;
  bool fast = (deg <= 64);
  if (fast) {
    float r = (lane < deg) ? payf[(size_t)(beg + lane) * 8 + 6] : -1e30f;
    float mm = r;
    #pragma unroll
    for (int sh = 1; sh < 64; sh <<= 1) mm = fmaxf(mm, __shfl_xor(mm, sh));
    M = mm;
    float ex = (lane < deg) ? __expf(r - M) : 0.f;
    float ss = ex;
    #pragma unroll
    for (int sh = 1; sh < 64; sh <<= 1) ss += __shfl_xor(ss, sh);
    inv = 1.f / (ss + 1e-16f);
    einv_reg = ex * inv;
    if (lane < deg) atts[elist[beg + lane]] = einv_reg;
  } else {
    float m_l = -1e30f;
    for (int jj = lane; jj < deg; jj += 64)
      m_l = fmaxf(m_l, payf[(size_t)(beg + jj) * 8 + 6]);
    #pragma unroll
    for (int sh = 1; sh < 64; sh <<= 1) m_l = fmaxf(m_l, __shfl_xor(m_l, sh));
    M = m_l;
    float s_l = 0.f;
    for (int jj = lane; jj < deg; jj += 64)
      s_l += __expf(payf[(size_t)(beg + jj) * 8 + 6] - M);
    #pragma unroll
    for (int sh = 1; sh < 64; sh <<= 1) s_l += __shfl_xor(s_l, sh);
    inv = 1.f / (s_l + 1e-16f);
    for (int jj = lane; jj < deg; jj += 64) {
      float r = payf[(size_t)(beg + jj) * 8 + 6];
      atts[elist[beg + jj]] = __expf(r - M) * inv;
    }
  }

  float agg[11];
  #pragma unroll
  for (int k = 0; k < 11; k++) agg[k] = 0.f;

  int j = half;
  for (; j + 2 < deg; j += 4) {
    uint4 a0 = pay[(size_t)(beg + j) * 2],     a1 = pay[(size_t)(beg + j) * 2 + 1];
    uint4 b0 = pay[(size_t)(beg + j + 2) * 2], b1 = pay[(size_t)(beg + j + 2) * 2 + 1];
    float xa = b2f(hpb[(size_t)(int)a1.w * 32 + d]);
    float xb = b2f(hpb[(size_t)(int)b1.w * 32 + d]);
    float ca = fast ? (1.f + __shfl(einv_reg, j))
                    : (1.f + __expf(__uint_as_float(a1.z) - M) * inv);
    float cb = fast ? (1.f + __shfl(einv_reg, j + 2))
                    : (1.f + __expf(__uint_as_float(b1.z) - M) * inv);
    float cxa = ca * xa, cxb = cb * xb;
    float eva[11], evb[11];
    unpack_pay(a0, a1, eva);
    unpack_pay(b0, b1, evb);
    #pragma unroll
    for (int k = 0; k < 11; k++) agg[k] += eva[k] * cxa + evb[k] * cxb;
  }
  for (; j < deg; j += 2) {
    uint4 q0 = pay[(size_t)(beg + j) * 2], q1 = pay[(size_t)(beg + j) * 2 + 1];
    float xs = b2f(hpb[(size_t)(int)q1.w * 32 + d]);
    float c = fast ? (1.f + __shfl(einv_reg, j))
                   : (1.f + __expf(__uint_as_float(q1.z) - M) * inv);
    float cx = c * xs;
    float ev[11];
    unpack_pay(q0, q1, ev);
    #pragma unroll
    for (int k = 0; k < 11; k++) agg[k] += ev[k] * cx;
  }

  #pragma unroll
  for (int k = 0; k < 11; k++) agg[k] += __shfl_xor(agg[k], 32);

  if (half == 0) {
    bf16* arow = Abuf + (size_t)n * 352 + d * 11;
    #pragma unroll
    for (int k = 0; k < 11; k++) arow[k] = tob(agg[k]);
  }
}

// ---------------- fused conv GEMM + epilogue (+ optional next-layer h_proj) ----------------
__global__ __launch_bounds__(128) void convfused_kernel(const short* __restrict__ A, const short* __restrict__ Wt,
                                                        const short* __restrict__ owB,
                                                        const float* __restrict__ hp, float* __restrict__ h,
                                                        const float* __restrict__ convb,
                                                        const float* __restrict__ s1w, const float* __restrict__ s1b,
                                                        const float* __restrict__ s2w, const float* __restrict__ s2b,
                                                        const float* __restrict__ outb,
                                                        const float* __restrict__ initw_next,
                                                        float* __restrict__ hp_out, unsigned short* __restrict__ hpb_out,
                                                        int N) {
  __shared__ short slo[32][40];
  __shared__ float sdelta[32][36];
  __shared__ float sskipw[128];
  __shared__ float sskipb[4];
  __shared__ float scb[32];
  __shared__ float sob[32];
  __shared__ float sw1[1024];
  int tid = threadIdx.x;
  if (tid < 64) sskipw[tid] = s1w[tid];
  if (tid >= 64 && tid < 128) sskipw[tid] = s2w[tid - 64];
  if (tid < 32) sob[tid] = outb[tid];
  if (tid >= 32 && tid < 64) scb[tid - 32] = (tid - 32 < 30) ? convb[tid - 32] : 0.f;
  if (tid >= 96 && tid < 100) sskipb[tid - 96] = (tid < 98) ? s1b[tid - 96] : s2b[tid - 98];
  if (initw_next) {
    for (int i = tid; i < 1024; i += 128) sw1[i] = initw_next[i];
  }
  __syncthreads();

  int wave = tid >> 6, lane = tid & 63;
  int r16 = lane & 15, kq = lane >> 4;
  int mbase = blockIdx.x * 32 + wave * 16;

  const short* arow = A + (size_t)(mbase + r16) * 352 + kq * 8;
  const short* b0p = Wt + (size_t)r16 * 352 + kq * 8;
  const short* b1p = b0p + 16 * 352;
  f32x4v acc0 = {0.f, 0.f, 0.f, 0.f}, acc1 = {0.f, 0.f, 0.f, 0.f};
  #pragma unroll
  for (int ks = 0; ks < 11; ks++) {
    bf16x8 af = *(const bf16x8*)(arow + ks * 32);
    bf16x8 b0 = *(const bf16x8*)(b0p + ks * 32);
    bf16x8 b1 = *(const bf16x8*)(b1p + ks * 32);
    acc0 = __builtin_amdgcn_mfma_f32_16x16x32_bf16(af, b0, acc0, 0, 0, 0);
    acc1 = __builtin_amdgcn_mfma_f32_16x16x32_bf16(af, b1, acc1, 0, 0, 0);
  }
  #pragma unroll
  for (int r = 0; r < 4; r++) {
    int row = wave * 16 + kq * 4 + r;
    slo[row][r16] = (short)tobu(fmaxf(acc0[r] + scb[r16], 0.f));
    if (r16 < 14) slo[row][16 + r16] = (short)tobu(fmaxf(acc1[r] + scb[16 + r16], 0.f));
  }
  __syncthreads();

  if (tid < 64) {
    int row = tid >> 1, jx = tid & 1;
    int grow = blockIdx.x * 32 + row;
    float a1 = sskipb[jx], a2 = sskipb[2 + jx];
    if (grow < N) {
      const float* hr = hp + (size_t)grow * 32;
      #pragma unroll
      for (int dd = 0; dd < 32; dd++) {
        float hv = hr[dd];
        a1 += hv * sskipw[dd*2 + jx];
        a2 += hv * sskipw[64 + dd*2 + jx];
      }
    }
    slo[row][30 + jx] = (short)tobu(tanh_fast(a1) * tanh_fast(a2));
  }
  __syncthreads();

  bf16x8 a2f = *(const bf16x8*)&slo[wave * 16 + r16][kq * 8];
  bf16x8 bo0 = *(const bf16x8*)(owB + lane * 8);
  bf16x8 bo1 = *(const bf16x8*)(owB + 512 + lane * 8);
  f32x4v d0 = {0.f, 0.f, 0.f, 0.f}, d1 = {0.f, 0.f, 0.f, 0.f};
  d0 = __builtin_amdgcn_mfma_f32_16x16x32_bf16(a2f, bo0, d0, 0, 0, 0);
  d1 = __builtin_amdgcn_mfma_f32_16x16x32_bf16(a2f, bo1, d1, 0, 0, 0);
  #pragma unroll
  for (int r = 0; r < 4; r++) {
    int row = wave * 16 + kq * 4 + r;
    sdelta[row][r16] = d0[r] + sob[r16];
    sdelta[row][16 + r16] = d1[r] + sob[16 + r16];
  }
  __syncthreads();

  int row = tid >> 2, col0 = (tid & 3) * 8;
  int grow = blockIdx.x * 32 + row;
  if (grow < N) {
    float* hr = h + (size_t)grow * 32 + col0;
    float4 ha = *(float4*)hr;
    float4 hb = *(float4*)(hr + 4);
    float4 da = *(float4*)&sdelta[row][col0];
    float4 db = *(float4*)&sdelta[row][col0 + 4];
    ha.x += da.x; ha.y += da.y; ha.z += da.z; ha.w += da.w;
    hb.x += db.x; hb.y += db.y; hb.z += db.z; hb.w += db.w;
    *(float4*)hr = ha;
    *(float4*)(hr + 4) = hb;
    *(float4*)&sdelta[row][col0] = ha;
    *(float4*)&sdelta[row][col0 + 4] = hb;
  }
  if (initw_next) {
    __syncthreads();
    if (grow < N) {
      float o[8];
      #pragma unroll
      for (int c = 0; c < 8; c++) o[c] = 0.f;
      #pragma unroll
      for (int k = 0; k < 32; k++) {
        float hv = sdelta[row][k];
        #pragma unroll
        for (int c = 0; c < 8; c++) o[c] += hv * sw1[k*32 + col0 + c];
      }
      float* hpo = hp_out + (size_t)grow * 32 + col0;
      unsigned short* hbo = hpb_out + (size_t)grow * 32 + col0;
      #pragma unroll
      for (int c = 0; c < 8; c++) { hpo[c] = o[c]; hbo[c] = tobu(o[c]); }
    }
  }
}

// ---------------- fused pool / outh / final head ----------------
__global__ __launch_bounds__(256) void pool2_kernel(const float* __restrict__ h, const int* __restrict__ gb,
                                                    const float* __restrict__ fw, const float* __restrict__ fb,
                                                    float* __restrict__ out0, float* __restrict__ outh) {
  __shared__ float part[8][32];
  __shared__ float pooled[32];
  int g = blockIdx.x;
  int s = gb[g], e = gb[g + 1];
  int grp = threadIdx.x >> 5, d = threadIdx.x & 31;
  float acc = 0.f;
  for (int n = s + grp; n < e; n += 8) {
    float v = h[(size_t)n * 32 + d];
    outh[(size_t)n * 32 + d] = v;
    acc += v;
  }
  part[grp][d] = acc;
  __syncthreads();
  if (threadIdx.x < 32) {
    float sum = 0.f;
    #pragma unroll
    for (int i = 0; i < 8; i++) sum += part[i][d];
    pooled[d] = sum / fmaxf((float)(e - s), 1.f);
  }
  __syncthreads();
  if (threadIdx.x < 32) {
    int jx = threadIdx.x;
    float o = fb[jx];
    #pragma unroll
    for (int dd = 0; dd < 32; dd++) o += pooled[dd] * fw[dd*32 + jx];
    out0[g * 32 + jx] = o;
  }
}

extern "C" void kernel_launch(void* const* d_in, const int* in_sizes, int n_in,
                              void* d_out, int out_size, void* d_ws, size_t ws_size,
                              hipStream_t stream) {
  (void)in_sizes; (void)n_in; (void)out_size; (void)ws_size;
  const float* x      = (const float*)d_in[0];
  const float* eattr  = (const float*)d_in[1];
  const int* eidx     = (const int*)d_in[2];
  const int* batch    = (const int*)d_in[3];
  const float* emb_w  = (const float*)d_in[4];
  const float* emb_b  = (const float*)d_in[5];
  const float* init_w = (const float*)d_in[6];
  const float* e1w    = (const float*)d_in[7];
  const float* e2w    = (const float*)d_in[8];
  const float* e3w    = (const float*)d_in[9];
  const float* e4w    = (const float*)d_in[10];
  const float* convw  = (const float*)d_in[11];
  const float* convb  = (const float*)d_in[12];
  const float* attv   = (const float*)d_in[13];
  const float* s1w    = (const float*)d_in[14];
  const float* s1b    = (const float*)d_in[15];
  const float* s2w    = (const float*)d_in[16];
  const float* s2b    = (const float*)d_in[17];
  const float* outw   = (const float*)d_in[18];
  const float* outb   = (const float*)d_in[19];
  const float* finw   = (const float*)d_in[20];
  const float* finb   = (const float*)d_in[21];

  char* ws = (char*)d_ws;
  size_t off = 0;
  auto take = [&](size_t bytes) -> char* {
    char* p = ws + off;
    off += (bytes + 255) & ~(size_t)255;
    return p;
  };
  float* h    = (float*)take((size_t)N_NODES * 32 * 4);
  float* hp   = (float*)take((size_t)N_NODES * 32 * 4);
  unsigned short* hpb = (unsigned short*)take((size_t)N_NODES * 32 * 2);
  uint4* pay0 = (uint4*)take((size_t)N_EDGES * 32);
  uint4* pay1 = (uint4*)take((size_t)N_EDGES * 32);
  bf16*  Abuf = (bf16*)take((size_t)N_PAD * 352 * 2);
  int*   deg  = (int*)take((size_t)N_NODES * 4);
  int*   offs = (int*)take((size_t)(N_NODES + 1) * 4);
  int*   cur  = (int*)take((size_t)N_NODES * 4);
  int*   elist= (int*)take((size_t)N_EDGES * 4);
  int*   gb   = (int*)take((size_t)(N_GR + 1) * 4);
  float* wE   = (float*)take((size_t)2 * 1352 * 4);
  bf16*  Wt   = (bf16*)take((size_t)2 * 32 * 352 * 2);
  bf16*  owB  = (bf16*)take((size_t)2048 * 2);

  float* out0 = (float*)d_out;
  float* outh = out0 + N_GR * 32;
  float* outa = outh + (size_t)N_NODES * 32;

  const int* srcA = eidx;
  const int* dstA = eidx + N_EDGES;

  prep_kernel<<<107, 256, 0, stream>>>(e1w, e2w, e3w, e4w, attv, convw, outw, batch, wE, Wt, owB, gb, deg);
  hist_kernel<<<(N_EDGES + 255) / 256, 256, 0, stream>>>(dstA, deg, N_EDGES);
  scan_kernel<<<1, 1024, 0, stream>>>(deg, offs, cur, N_NODES);
  edge_mlp_kernel<<<(N_EDGES + 255) / 256, 256, 0, stream>>>(
      eattr, srcA, dstA, cur, elist, wE, wE + 1352, pay0, pay1, N_EDGES);
  emb_hproj_kernel<<<(N_NODES + 7) / 8, 256, 0, stream>>>(x, emb_w, emb_b, init_w, h, hp, hpb, N_NODES);

  for (int l = 0; l < 2; l++) {
    uint4* pay = (l == 0) ? pay0 : pay1;
    edge_raw_kernel<<<(N_EDGES + 255) / 256, 256, 0, stream>>>(
        pay, hpb, wE + l * 1352 + 1320, N_EDGES);
    node_kernel<<<N_PAD / 4, 256, 0, stream>>>(offs, elist, pay, hpb,
                                               Abuf, outa + (size_t)l * N_EDGES, N_NODES);
    convfused_kernel<<<N_PAD / 32, 128, 0, stream>>>(
        (const short*)Abuf, (const short*)Wt + (size_t)l * 32 * 352, (const short*)owB + (size_t)l * 1024,
        hp, h, convb + l * 30, s1w + l * 64, s1b + l * 2, s2w + l * 64, s2b + l * 2,
        outb + l * 32,
        (l == 0) ? (init_w + 1024) : nullptr, hp, hpb, N_NODES);
  }

  pool2_kernel<<<N_GR, 256, 0, stream>>>(h, gb, finw, finb, out0, outh);
}